// Round 17
// baseline (215.857 us; speedup 1.0000x reference)
//
#include <hip/hip_runtime.h>
#include <hip/hip_bf16.h>

#define TOKENS 8192
#define DM 1024
#define DFF 4096
#define NE 8
#define CAP 1280
#define ECAP (NE*CAP)                     // 10240
#define OUT_ELEMS ((size_t)NE*CAP*DFF)    // 41,943,040
#define CMB_ELEMS ((size_t)TOKENS*NE*CAP) // 83,886,080
#define ZROW TOKENS                       // index of appended zero row in xbf
#define GBK 32                            // GEMM K-tile

typedef __attribute__((ext_vector_type(8))) short short8;
typedef __attribute__((ext_vector_type(16))) float f32x16;
typedef __attribute__((ext_vector_type(4))) float f4;   // native vec for nontemporal

__device__ inline ushort f2bf(float f) {
    __hip_bfloat16 h = __float2bfloat16(f);
    return *reinterpret_cast<ushort*>(&h);
}

union U8C { short8 s; ushort u[8]; };

__device__ __forceinline__ void gload16(const ushort* g, short* l) {
    __builtin_amdgcn_global_load_lds(
        (const __attribute__((address_space(1))) void*)g,
        (__attribute__((address_space(3))) void*)l, 16, 0, 0);
}

// ---------------- gate: logits, softmax, top1, x->bf16 fused ----------------
__global__ __launch_bounds__(256) void gate_kernel(const float* __restrict__ x,
        const float* __restrict__ gw, float* __restrict__ probs8, int* __restrict__ top1,
        ushort* __restrict__ xbf) {
    int wave = threadIdx.x >> 6;
    int lane = threadIdx.x & 63;
    int t = blockIdx.x * 4 + wave;
    const float* xrow = x + (size_t)t * DM;
    float4 xv[4];
    #pragma unroll
    for (int j = 0; j < 4; ++j) xv[j] = *(const float4*)(xrow + lane * 4 + j * 256);
    ushort* xbrow = xbf + (size_t)t * DM;
    #pragma unroll
    for (int j = 0; j < 4; ++j) {
        ushort4 o;
        o.x = f2bf(xv[j].x); o.y = f2bf(xv[j].y); o.z = f2bf(xv[j].z); o.w = f2bf(xv[j].w);
        *(ushort4*)(xbrow + lane * 4 + j * 256) = o;
    }
    float logit[8];
    #pragma unroll
    for (int e = 0; e < 8; ++e) {
        const float* g = gw + e * DM;
        float s = 0.f;
        #pragma unroll
        for (int j = 0; j < 4; ++j) {
            float4 gv = *(const float4*)(g + lane * 4 + j * 256);
            s += xv[j].x * gv.x + xv[j].y * gv.y + xv[j].z * gv.z + xv[j].w * gv.w;
        }
        #pragma unroll
        for (int off = 32; off >= 1; off >>= 1) s += __shfl_xor(s, off);
        logit[e] = s;
    }
    if (lane == 0) {
        int bi = 0; float bv = logit[0];
        #pragma unroll
        for (int e = 1; e < 8; ++e) if (logit[e] > bv) { bv = logit[e]; bi = e; }
        float se = 0.f, p[8];
        #pragma unroll
        for (int e = 0; e < 8; ++e) { p[e] = expf(logit[e] - bv); se += p[e]; }
        float inv = 1.f / se;
        #pragma unroll
        for (int e = 0; e < 8; ++e) probs8[t * 8 + e] = p[e] * inv;
        top1[t] = bi;
    }
    if (blockIdx.x == 0) {   // zero row for empty capacity slots
        ushort4 z; z.x = z.y = z.z = z.w = 0;
        *(ushort4*)(xbf + (size_t)ZROW * DM + threadIdx.x * 4) = z;
    }
}

// ---------------- rank: per-expert cumsum scan (standalone, 1 block) ----------------
__global__ __launch_bounds__(512) void rank_kernel(const int* __restrict__ top1,
        const float* __restrict__ probs8, int* __restrict__ slot_token,
        int* __restrict__ pos, int* __restrict__ cnts, float* __restrict__ laux_out) {
    int w8 = threadIdx.x >> 6;     // wave = expert
    int lane = threadIdx.x & 63;
    const int tid = threadIdx.x;
    __shared__ int t1s[TOKENS];    // 32 KB
    __shared__ float red[64];
    __shared__ int cnt_sh[8];
    for (int i = tid; i < TOKENS; i += 512) t1s[i] = top1[i];
    for (int i = tid; i < ECAP; i += 512) slot_token[i] = ZROW;
    for (int i = tid; i < TOKENS; i += 512) pos[i] = -1;

    float ps[8];
    #pragma unroll
    for (int e = 0; e < 8; ++e) ps[e] = 0.f;
    for (int t = tid; t < TOKENS; t += 512) {
        float4 a = *(const float4*)(probs8 + t * 8);
        float4 b = *(const float4*)(probs8 + t * 8 + 4);
        ps[0] += a.x; ps[1] += a.y; ps[2] += a.z; ps[3] += a.w;
        ps[4] += b.x; ps[5] += b.y; ps[6] += b.z; ps[7] += b.w;
    }
    #pragma unroll
    for (int e = 0; e < 8; ++e) {
        #pragma unroll
        for (int off = 32; off >= 1; off >>= 1) ps[e] += __shfl_xor(ps[e], off);
    }
    if (lane == 0) {
        #pragma unroll
        for (int e = 0; e < 8; ++e) red[w8 * 8 + e] = ps[e];
    }
    __syncthreads();

    int base = 0;
    for (int t0 = 0; t0 < TOKENS; t0 += 256) {
        #pragma unroll
        for (int q = 0; q < 4; ++q) {
            int t = t0 + q * 64 + lane;
            bool mine = (t1s[t] == w8);
            unsigned long long m = __ballot(mine);
            if (mine) {
                int r = base + __popcll(m & ((1ull << lane) - 1ull));
                if (r < CAP) { slot_token[w8 * CAP + r] = t; pos[t] = w8 * CAP + r; }
            }
            base += __popcll(m);
        }
    }
    if (lane == 0) { cnt_sh[w8] = base; cnts[w8] = (base < CAP) ? base : CAP; }
    __syncthreads();
    if (tid == 0) {
        float la = 0.f;
        #pragma unroll
        for (int e = 0; e < 8; ++e) {
            float me = 0.f;
            #pragma unroll
            for (int wv = 0; wv < 8; ++wv) me += red[wv * 8 + e];
            la += (me / (float)TOKENS) * ((float)cnt_sh[e] / (float)TOKENS);
        }
        laux_out[0] = la * (float)NE;
    }
}

// ---------------- gathered GEMM v6: on-the-fly W f32->bf16 (no wtbf intermediate) ----
// 256x128 tile, 512 thr (8 waves 4x2; per-wave 64x64 = 2x2 32x32 frags, acc 64 VGPR).
// 3 LDS buffers x 24 KB -> 2 blocks/CU at launch_bounds(512,4).
// Grid 1280: e = bid&7 (XCD spread), nt fastest, mt slowest (empty tiles last).
// LDS 16B slot s: (row = s>>2, chunk = (s&3)^((s>>3)&3)); read slot(r,c) =
// r*4 + (c ^ ((r>>1)&3)) -> uniform bank coverage (conflict-free). LDS image
// identical to v4b; compute side unchanged.
// A: depth-2 gload_lds (unchanged). B: per thread 8 f32 k-column loads from W
// (wave-coalesced 64B segments), cvt+pack, one ds_write_b128 to slot tid.
// Waits: the compiler's waitcnt pass inserts the exact vmcnt before the pack
// (plain-C loads are dep-tracked; it counts the intervening gload_lds/stores),
// and that wait subsumes retiring tile-t's A-gloads (strictly older than the
// B(t+1) regs). Explicit lgkmcnt(0) before the leading barrier covers the
// ds_write visibility. In-loop combine stores kept (R13: moving them out +29us).
__global__ __launch_bounds__(512, 4) void gemm_kernel(
    const ushort* __restrict__ xbf,        // [8193][1024] bf16 (row 8192 = zeros)
    const float*  __restrict__ w,          // [8][1024][4096] f32 (k-major!)
    const float*  __restrict__ bias,       // [8][4096]
    const int*    __restrict__ slot_token, // [8][1280], empty -> ZROW
    const int*    __restrict__ cnts,       // [8] rows actually filled (capped)
    float* __restrict__ out,               // [8][1280][4096]
    const int*    __restrict__ pos,        // [8192] token -> flat slot (or -1)
    const float*  __restrict__ probs8,     // [8192][8]
    float* __restrict__ cmb,               // [8192][10240]
    int do_combine)
{
    const int bid = blockIdx.x;
    const int e   = bid & 7;
    const int rem = bid >> 3;     // 0..159
    const int nt  = rem & 31;     // fastest -> B-panel reuse
    const int mt  = rem >> 5;     // 0..4, slowest -> empty tiles last
    __shared__ __align__(16) short lds[3][12288];   // 72 KiB
    const int tid  = threadIdx.x;          // 0..511
    const int lane = tid & 63;
    const int wave = tid >> 6;              // 0..7
    const int wr = wave >> 1;               // 0..3 -> 64-row band
    const int wc = wave & 1;                // 0..1 -> 64-col band
    const int ln31 = lane & 31, lh = lane >> 5;
    const int tbeg = bid * 8;
    const bool has_cmb = do_combine && (bid < 1024);

    float* orow = out + ((size_t)(e * CAP + mt * 256)) * DFF + (size_t)nt * 128;

    // rolling combine state: 5 parts per token (512 thr x 5 x f4 = 10240 floats)
    f4* cmb_p = (f4*)cmb + (size_t)tbeg * (ECAP / 4);
    int kpart = 0, ntok = 0;
    int cur_p = -1, nxt_p = -1;
    float cur_val = 0.f, nxt_val = 0.f;
    if (has_cmb) {
        cur_p = pos[tbeg];
        { int ee = (cur_p < 0) ? 0 : (cur_p / CAP); cur_val = probs8[tbeg * 8 + ee]; }
        nxt_p = pos[tbeg + 1];
        { int ee = (nxt_p < 0) ? 0 : (nxt_p / CAP); nxt_val = probs8[(tbeg + 1) * 8 + ee]; }
    }
    #define CSTORE() do { \
        int c_ = tid + kpart * 512; \
        int b4_ = c_ * 4; \
        f4 v_; \
        v_.x = (b4_ + 0 == cur_p) ? cur_val : 0.f; \
        v_.y = (b4_ + 1 == cur_p) ? cur_val : 0.f; \
        v_.z = (b4_ + 2 == cur_p) ? cur_val : 0.f; \
        v_.w = (b4_ + 3 == cur_p) ? cur_val : 0.f; \
        __builtin_nontemporal_store(v_, cmb_p + c_); \
        if (++kpart == 5) { \
            kpart = 0; cmb_p += ECAP / 4; ++ntok; \
            cur_p = nxt_p; cur_val = nxt_val; \
            if (ntok + 1 < 8) { \
                nxt_p = pos[tbeg + ntok + 1]; \
                int ee_ = (nxt_p < 0) ? 0 : (nxt_p / CAP); \
                nxt_val = probs8[(tbeg + ntok + 1) * 8 + ee_]; \
            } \
        } \
    } while (0)

    if (mt * 256 >= cnts[e]) {
        // -------- empty-tile fast path: out = bias, combine burst --------
        int c4 = tid & 31;            // 32 f4 per 128-col row
        int r0b = tid >> 5;           // 0..15
        f4 bv4 = *(const f4*)(bias + e * DFF + nt * 128 + c4 * 4);
        for (int r = r0b; r < 256; r += 16)
            __builtin_nontemporal_store(bv4, (f4*)(orow + (size_t)r * DFF + c4 * 4));
        if (has_cmb) { while (ntok < 8) CSTORE(); }
        return;
    }

    // A staging: 2 x 16B gload_lds per thread per K-tile (rows r0a, r0a+128)
    const int r0a = tid >> 2;                       // 0..127
    const int kg = (tid & 3) ^ ((tid >> 3) & 3);    // chunk held by slot tid
    const int tokA0 = slot_token[e * CAP + mt * 256 + r0a];
    const int tokA1 = slot_token[e * CAP + mt * 256 + 128 + r0a];
    const ushort* aptr0 = xbf + (size_t)tokA0 * DM + kg * 8;
    const ushort* aptr1 = xbf + (size_t)tokA1 * DM + kg * 8;
    // B source: k-column of 8 f32 at n = nt*128 + r0a, k = t*32 + kg*8 + j
    const float* bsrc = w + (size_t)e * DM * DFF + (size_t)(kg * 8) * DFF
                          + (size_t)nt * 128 + r0a;

    #define STAGE_A(T) do { \
        short* base_ = &lds[(T) % 3][0]; \
        size_t ko_ = (size_t)(T) * GBK; \
        gload16(aptr0 + ko_, base_ + tid * 8); \
        gload16(aptr1 + ko_, base_ + 4096 + tid * 8); \
    } while (0)

    float br[8];
    #define BLOAD(T) do { \
        const float* bp_ = bsrc + (size_t)(T) * GBK * DFF; \
        _Pragma("unroll") \
        for (int j = 0; j < 8; ++j) br[j] = bp_[(size_t)j * DFF]; \
    } while (0)
    #define BWRITE(T) do { \
        U8C u_; \
        _Pragma("unroll") \
        for (int j = 0; j < 8; ++j) u_.u[j] = f2bf(br[j]); \
        *(short8*)(&lds[(T) % 3][8192 + tid * 8]) = u_.s; \
    } while (0)

    // fragment LDS offsets (shorts): A [s*2+mi], B [s*2+ni]
    int aoff[4], boff[4];
    #pragma unroll
    for (int s = 0; s < 2; ++s) {
        #pragma unroll
        for (int mi = 0; mi < 2; ++mi) {
            int r = wr * 64 + mi * 32 + ln31;            // 0..255
            int c = lh + 2 * s;
            aoff[s * 2 + mi] = (r * 4 + (c ^ ((r >> 1) & 3))) * 8;
        }
        #pragma unroll
        for (int ni = 0; ni < 2; ++ni) {
            int rn = wc * 64 + ni * 32 + ln31;           // 0..127
            int c = lh + 2 * s;
            boff[s * 2 + ni] = 8192 + (rn * 4 + (c ^ ((rn >> 1) & 3))) * 8;
        }
    }

    f32x16 acc[2][2];
    #pragma unroll
    for (int mi = 0; mi < 2; ++mi)
        #pragma unroll
        for (int ni = 0; ni < 2; ++ni)
            acc[mi][ni] = (f32x16)(0.f);

    // prologue: A(0),B(0),A(1); write B(0); B(1) in flight
    STAGE_A(0); BLOAD(0); STAGE_A(1);
    BWRITE(0);                 // compiler-inserted vmcnt retires B(0) (and A(0))
    BLOAD(1);

    for (int t = 0; t < 32; ++t) {
        if (t < 30) STAGE_A(t + 2);
        if (t < 31) BWRITE(t + 1);     // exact compiler vmcnt; subsumes A(t) retire
        if (t < 30) BLOAD(t + 2);
        asm volatile("s_waitcnt lgkmcnt(0)" ::: "memory");   // ds_write visible
        __builtin_amdgcn_s_barrier();            // all waves' tile-t data in LDS
        __builtin_amdgcn_sched_barrier(0);

        const short* L = &lds[t % 3][0];
        __builtin_amdgcn_s_setprio(1);
        #pragma unroll
        for (int s = 0; s < 2; ++s) {
            short8 af[2], bfr[2];
            #pragma unroll
            for (int ni = 0; ni < 2; ++ni) bfr[ni] = *(const short8*)(L + boff[s * 2 + ni]);
            #pragma unroll
            for (int mi = 0; mi < 2; ++mi) af[mi] = *(const short8*)(L + aoff[s * 2 + mi]);
            #pragma unroll
            for (int mi = 0; mi < 2; ++mi)
                #pragma unroll
                for (int ni = 0; ni < 2; ++ni)
                    acc[mi][ni] = __builtin_amdgcn_mfma_f32_32x32x16_bf16(af[mi], bfr[ni], acc[mi][ni], 0, 0, 0);
        }
        __builtin_amdgcn_s_setprio(0);
        if (has_cmb) CSTORE();                   // 1 store/iter (32 of 40)
        __builtin_amdgcn_sched_barrier(0);
        asm volatile("" ::: "memory");
        __builtin_amdgcn_s_barrier();            // buf[t%3] free for re-stage
        asm volatile("" ::: "memory");
    }
    #undef STAGE_A
    #undef BLOAD
    #undef BWRITE

    // epilogue: out tile + remaining 8 combine stores
    #pragma unroll
    for (int ni = 0; ni < 2; ++ni) {
        int c = wc * 64 + ni * 32 + ln31;
        float bv = bias[e * DFF + nt * 128 + c];
        #pragma unroll
        for (int mi = 0; mi < 2; ++mi) {
            #pragma unroll
            for (int reg = 0; reg < 16; ++reg) {
                int r = wr * 64 + mi * 32 + (reg & 3) + 8 * (reg >> 2) + 4 * lh;
                __builtin_nontemporal_store(acc[mi][ni][reg] + bv,
                    orow + (size_t)r * DFF + c);
            }
        }
    }
    if (has_cmb) { while (ntok < 8) CSTORE(); }
    #undef CSTORE
}

// ---------------- standalone combine (fallback when ws too small) ----------------
__global__ __launch_bounds__(256) void combine_kernel(const int* __restrict__ pos,
        const float* __restrict__ probs8, float* __restrict__ cmb) {
    int tok = blockIdx.x;
    int p = pos[tok];
    int e = p / CAP;
    float val = probs8[tok * 8 + (e < 0 ? 0 : e)];
    f4* row = (f4*)(cmb + (size_t)tok * ECAP);
    #pragma unroll
    for (int k = 0; k < 10; ++k) {
        int c = threadIdx.x + k * 256;
        int b4 = c * 4;
        f4 v;
        v.x = (b4 + 0 == p) ? val : 0.f;
        v.y = (b4 + 1 == p) ? val : 0.f;
        v.z = (b4 + 2 == p) ? val : 0.f;
        v.w = (b4 + 3 == p) ? val : 0.f;
        __builtin_nontemporal_store(v, row + c);
    }
}

extern "C" void kernel_launch(void* const* d_in, const int* in_sizes, int n_in,
                              void* d_out, int out_size, void* d_ws, size_t ws_size,
                              hipStream_t stream) {
    const float* x  = (const float*)d_in[0];
    const float* gw = (const float*)d_in[1];
    const float* ew = (const float*)d_in[2];
    const float* eb = (const float*)d_in[3];

    float* out = (float*)d_out;                 // [8][1280][4096]
    float* cmb = out + OUT_ELEMS;               // [8192][8][1280]
    float* laux_out = cmb + CMB_ELEMS;          // scalar

    // small scratch at the head of d_ws
    float* probs8 = (float*)d_ws;               // 8192*8
    int* top1 = (int*)(probs8 + TOKENS * 8);    // 8192
    int* slot_token = top1 + TOKENS;            // 10240
    int* pos = slot_token + ECAP;               // 8192
    int* cnts = pos + TOKENS;                   // 8

    // bf16 x scratch: prefer d_ws (enables in-gemm combine overlap);
    // fall back to the cmb region (then combine runs standalone after gemm).
    const size_t SMALL = 1 << 20;
    const size_t XBF_ELEMS_ = (size_t)(TOKENS + 1) * DM;     // 8,389,632 ushort
    bool big_ws = ws_size >= SMALL + XBF_ELEMS_ * sizeof(ushort);
    ushort* xbf = big_ws ? (ushort*)((char*)d_ws + SMALL) : (ushort*)cmb;

    gate_kernel<<<TOKENS / 4, 256, 0, stream>>>(x, gw, probs8, top1, xbf);
    rank_kernel<<<1, 512, 0, stream>>>(top1, probs8, slot_token, pos, cnts, laux_out);
    if (big_ws) {
        gemm_kernel<<<1280, 512, 0, stream>>>(xbf, ew, eb, slot_token, cnts, out,
                                              pos, probs8, cmb, 1);
    } else {
        gemm_kernel<<<1280, 512, 0, stream>>>(xbf, ew, eb, slot_token, cnts, out,
                                              pos, probs8, cmb, 0);
        combine_kernel<<<TOKENS, 256, 0, stream>>>(pos, probs8, cmb);
    }
}

// Round 18
// 186.714 us; speedup vs baseline: 1.1561x; 1.1561x over previous
//
#include <hip/hip_runtime.h>
#include <hip/hip_bf16.h>

#define TOKENS 8192
#define DM 1024
#define DFF 4096
#define NE 8
#define CAP 1280
#define ECAP (NE*CAP)                     // 10240
#define OUT_ELEMS ((size_t)NE*CAP*DFF)    // 41,943,040
#define CMB_ELEMS ((size_t)TOKENS*NE*CAP) // 83,886,080
#define ZROW TOKENS                       // index of appended zero row in xbf
#define GBK 32                            // GEMM K-tile

typedef __attribute__((ext_vector_type(8))) short short8;
typedef __attribute__((ext_vector_type(16))) float f32x16;
typedef __attribute__((ext_vector_type(4))) float f4;   // native vec for nontemporal

__device__ inline ushort f2bf(float f) {
    __hip_bfloat16 h = __float2bfloat16(f);
    return *reinterpret_cast<ushort*>(&h);
}

__device__ __forceinline__ void gload16(const ushort* g, short* l) {
    __builtin_amdgcn_global_load_lds(
        (const __attribute__((address_space(1))) void*)g,
        (__attribute__((address_space(3))) void*)l, 16, 0, 0);
}

// ---------------- gate: logits, softmax, top1, x->bf16 fused ----------------
__global__ __launch_bounds__(256) void gate_kernel(const float* __restrict__ x,
        const float* __restrict__ gw, float* __restrict__ probs8, int* __restrict__ top1,
        ushort* __restrict__ xbf) {
    int wave = threadIdx.x >> 6;
    int lane = threadIdx.x & 63;
    int t = blockIdx.x * 4 + wave;
    const float* xrow = x + (size_t)t * DM;
    float4 xv[4];
    #pragma unroll
    for (int j = 0; j < 4; ++j) xv[j] = *(const float4*)(xrow + lane * 4 + j * 256);
    ushort* xbrow = xbf + (size_t)t * DM;
    #pragma unroll
    for (int j = 0; j < 4; ++j) {
        ushort4 o;
        o.x = f2bf(xv[j].x); o.y = f2bf(xv[j].y); o.z = f2bf(xv[j].z); o.w = f2bf(xv[j].w);
        *(ushort4*)(xbrow + lane * 4 + j * 256) = o;
    }
    float logit[8];
    #pragma unroll
    for (int e = 0; e < 8; ++e) {
        const float* g = gw + e * DM;
        float s = 0.f;
        #pragma unroll
        for (int j = 0; j < 4; ++j) {
            float4 gv = *(const float4*)(g + lane * 4 + j * 256);
            s += xv[j].x * gv.x + xv[j].y * gv.y + xv[j].z * gv.z + xv[j].w * gv.w;
        }
        #pragma unroll
        for (int off = 32; off >= 1; off >>= 1) s += __shfl_xor(s, off);
        logit[e] = s;
    }
    if (lane == 0) {
        int bi = 0; float bv = logit[0];
        #pragma unroll
        for (int e = 1; e < 8; ++e) if (logit[e] > bv) { bv = logit[e]; bi = e; }
        float se = 0.f, p[8];
        #pragma unroll
        for (int e = 0; e < 8; ++e) { p[e] = expf(logit[e] - bv); se += p[e]; }
        float inv = 1.f / se;
        #pragma unroll
        for (int e = 0; e < 8; ++e) probs8[t * 8 + e] = p[e] * inv;
        top1[t] = bi;
    }
    if (blockIdx.x == 0) {   // zero row for empty capacity slots
        ushort4 z; z.x = z.y = z.z = z.w = 0;
        *(ushort4*)(xbf + (size_t)ZROW * DM + threadIdx.x * 4) = z;
    }
}

// ---------------- cvt_w (blocks 1..16384) + rank (block 0), fused ----------------
__global__ __launch_bounds__(512) void cvtw_rank_kernel(
        const float* __restrict__ w, ushort* __restrict__ wt,
        const int* __restrict__ top1, const float* __restrict__ probs8,
        int* __restrict__ slot_token, int* __restrict__ pos,
        int* __restrict__ cnts, float* __restrict__ laux_out) {
    __shared__ __align__(16) char smem[TOKENS * 4 + 64 * 4 + 8 * 4];
    const int tid = threadIdx.x;
    if (blockIdx.x == 0) {
        // ---------------- rank ----------------
        int* t1s = (int*)smem;                       // 32 KB
        float* red = (float*)(smem + TOKENS * 4);    // 8 waves x 8 experts
        int* cnt_sh = (int*)(smem + TOKENS * 4 + 64 * 4);
        int w8 = tid >> 6;         // wave = expert
        int lane = tid & 63;
        for (int i = tid; i < TOKENS; i += 512) t1s[i] = top1[i];
        for (int i = tid; i < ECAP; i += 512) slot_token[i] = ZROW;
        for (int i = tid; i < TOKENS; i += 512) pos[i] = -1;

        float ps[8];
        #pragma unroll
        for (int e = 0; e < 8; ++e) ps[e] = 0.f;
        for (int t = tid; t < TOKENS; t += 512) {
            float4 a = *(const float4*)(probs8 + t * 8);
            float4 b = *(const float4*)(probs8 + t * 8 + 4);
            ps[0] += a.x; ps[1] += a.y; ps[2] += a.z; ps[3] += a.w;
            ps[4] += b.x; ps[5] += b.y; ps[6] += b.z; ps[7] += b.w;
        }
        #pragma unroll
        for (int e = 0; e < 8; ++e) {
            #pragma unroll
            for (int off = 32; off >= 1; off >>= 1) ps[e] += __shfl_xor(ps[e], off);
        }
        if (lane == 0) {
            #pragma unroll
            for (int e = 0; e < 8; ++e) red[w8 * 8 + e] = ps[e];
        }
        __syncthreads();

        int base = 0;
        for (int t0 = 0; t0 < TOKENS; t0 += 256) {
            #pragma unroll
            for (int q = 0; q < 4; ++q) {
                int t = t0 + q * 64 + lane;
                bool mine = (t1s[t] == w8);
                unsigned long long m = __ballot(mine);
                if (mine) {
                    int r = base + __popcll(m & ((1ull << lane) - 1ull));
                    if (r < CAP) { slot_token[w8 * CAP + r] = t; pos[t] = w8 * CAP + r; }
                }
                base += __popcll(m);
            }
        }
        if (lane == 0) { cnt_sh[w8] = base; cnts[w8] = (base < CAP) ? base : CAP; }
        __syncthreads();
        if (tid == 0) {
            float la = 0.f;
            #pragma unroll
            for (int e = 0; e < 8; ++e) {
                float me = 0.f;
                #pragma unroll
                for (int wv = 0; wv < 8; ++wv) me += red[wv * 8 + e];
                la += (me / (float)TOKENS) * ((float)cnt_sh[e] / (float)TOKENS);
            }
            laux_out[0] = la * (float)NE;
        }
        return;
    }
    // ---------------- cvt_w tile: 64n x 32k ----------------
    float (*tile)[65] = (float(*)[65])smem;          // [32k][64n] padded
    int b = blockIdx.x - 1;                          // 0..16383
    int e = b >> 11;                                 // 2048 tiles/expert
    int rem = b & 2047;
    int n0 = (rem & 63) * 64;
    int k0 = (rem >> 6) * 32;
    const float* we = w + (size_t)e * DM * DFF;
    int c = tid & 63, r0 = tid >> 6;                 // load: 8 k-rows/pass
    #pragma unroll
    for (int i = 0; i < 4; ++i) {
        int r = r0 + i * 8;
        tile[r][c] = we[(size_t)(k0 + r) * DFF + n0 + c];
    }
    __syncthreads();
    ushort* wte = wt + (size_t)e * DFF * DM;
    int kc = tid & 31, nr0 = tid >> 5;               // store: 16 n-rows/pass
    #pragma unroll
    for (int i = 0; i < 4; ++i) {
        int nr = nr0 + i * 16;
        wte[(size_t)(n0 + nr) * DM + k0 + kc] = f2bf(tile[kc][nr]);
    }
}

// ---------------- gathered GEMM v4b: 256x128 tile, 2 blocks/CU, path-exact vmcnt ----
// (byte-identical to R12/R14/R16 — the empirical optimum of this decomposition)
// 512 thr (8 waves 4x2; per-wave 64x64 = 2x2 32x32 frags, acc 64 VGPR).
// 3 LDS buffers x 24 KB = 72 KB -> 2 blocks/CU at launch_bounds(512,4).
// Grid 1280: e = bid&7 (XCD spread), nt fastest, mt slowest (empty tiles last).
// LDS 16B slot s: (row = s>>2, chunk = (s&3)^((s>>3)&3)); read slot(r,c) =
// r*4 + (c ^ ((r>>1)&3)) -> uniform bank coverage (conflict-free).
// Pipeline depth-2-ahead: stage(t+2); 3 loads/thread/tile. vmcnt PATH-EXACT:
//  with combine: waits 6/7/8/5/2 (t=0/1/steady/30/31); without: 6/6/6/3/0.
// In-loop combine stores are FREE here (R13: moving them out +29us; R15:
// launch-fusion via device sync +206us; R17: on-the-fly W cvt +29us).
__global__ __launch_bounds__(512, 4) void gemm_kernel(
    const ushort* __restrict__ xbf,        // [8193][1024] bf16 (row 8192 = zeros)
    const ushort* __restrict__ wt,         // [8][4096][1024] bf16 (n-major)
    const float*  __restrict__ bias,       // [8][4096]
    const int*    __restrict__ slot_token, // [8][1280], empty -> ZROW
    const int*    __restrict__ cnts,       // [8] rows actually filled (capped)
    float* __restrict__ out,               // [8][1280][4096]
    const int*    __restrict__ pos,        // [8192] token -> flat slot (or -1)
    const float*  __restrict__ probs8,     // [8192][8]
    float* __restrict__ cmb,               // [8192][10240]
    int do_combine)
{
    const int bid = blockIdx.x;
    const int e   = bid & 7;
    const int rem = bid >> 3;     // 0..159
    const int nt  = rem & 31;     // fastest -> B-panel reuse
    const int mt  = rem >> 5;     // 0..4, slowest -> empty tiles last
    __shared__ __align__(16) short lds[3][12288];   // 72 KiB
    const int tid  = threadIdx.x;          // 0..511
    const int lane = tid & 63;
    const int wave = tid >> 6;              // 0..7
    const int wr = wave >> 1;               // 0..3 -> 64-row band
    const int wc = wave & 1;                // 0..1 -> 64-col band
    const int ln31 = lane & 31, lh = lane >> 5;
    const int tbeg = bid * 8;
    const bool has_cmb = do_combine && (bid < 1024);

    float* orow = out + ((size_t)(e * CAP + mt * 256)) * DFF + (size_t)nt * 128;

    // rolling combine state: 5 parts per token (512 thr x 5 x f4 = 10240 floats)
    f4* cmb_p = (f4*)cmb + (size_t)tbeg * (ECAP / 4);
    int kpart = 0, ntok = 0;
    int cur_p = -1, nxt_p = -1;
    float cur_val = 0.f, nxt_val = 0.f;
    if (has_cmb) {
        cur_p = pos[tbeg];
        { int ee = (cur_p < 0) ? 0 : (cur_p / CAP); cur_val = probs8[tbeg * 8 + ee]; }
        nxt_p = pos[tbeg + 1];
        { int ee = (nxt_p < 0) ? 0 : (nxt_p / CAP); nxt_val = probs8[(tbeg + 1) * 8 + ee]; }
    }
    #define CSTORE() do { \
        int c_ = tid + kpart * 512; \
        int b4_ = c_ * 4; \
        f4 v_; \
        v_.x = (b4_ + 0 == cur_p) ? cur_val : 0.f; \
        v_.y = (b4_ + 1 == cur_p) ? cur_val : 0.f; \
        v_.z = (b4_ + 2 == cur_p) ? cur_val : 0.f; \
        v_.w = (b4_ + 3 == cur_p) ? cur_val : 0.f; \
        __builtin_nontemporal_store(v_, cmb_p + c_); \
        if (++kpart == 5) { \
            kpart = 0; cmb_p += ECAP / 4; ++ntok; \
            cur_p = nxt_p; cur_val = nxt_val; \
            if (ntok + 1 < 8) { \
                nxt_p = pos[tbeg + ntok + 1]; \
                int ee_ = (nxt_p < 0) ? 0 : (nxt_p / CAP); \
                nxt_val = probs8[(tbeg + ntok + 1) * 8 + ee_]; \
            } \
        } \
    } while (0)

    if (mt * 256 >= cnts[e]) {
        // -------- empty-tile fast path: out = bias, combine burst --------
        int c4 = tid & 31;            // 32 f4 per 128-col row
        int r0b = tid >> 5;           // 0..15
        f4 bv4 = *(const f4*)(bias + e * DFF + nt * 128 + c4 * 4);
        for (int r = r0b; r < 256; r += 16)
            __builtin_nontemporal_store(bv4, (f4*)(orow + (size_t)r * DFF + c4 * 4));
        if (has_cmb) { while (ntok < 8) CSTORE(); }
        return;
    }

    // staging: 3 x 16B per thread per K-tile (A rows r0a, r0a+128; B row r0a)
    const int r0a = tid >> 2;                       // 0..127
    const int kg = (tid & 3) ^ ((tid >> 3) & 3);    // inverse swizzle chunk
    const int tokA0 = slot_token[e * CAP + mt * 256 + r0a];
    const int tokA1 = slot_token[e * CAP + mt * 256 + 128 + r0a];
    const ushort* aptr0 = xbf + (size_t)tokA0 * DM + kg * 8;
    const ushort* aptr1 = xbf + (size_t)tokA1 * DM + kg * 8;
    const ushort* bptr  = wt + ((size_t)e * DFF + (size_t)nt * 128 + r0a) * DM + kg * 8;

    #define STAGE(T, BUF) do { \
        short* base_ = &lds[BUF][0]; \
        size_t ko_ = (size_t)(T) * GBK; \
        gload16(aptr0 + ko_, base_ + tid * 8); \
        gload16(aptr1 + ko_, base_ + 4096 + tid * 8); \
        gload16(bptr  + ko_, base_ + 8192 + tid * 8); \
    } while (0)

    // fragment LDS offsets (shorts): A [s*2+mi], B [s*2+ni]
    int aoff[4], boff[4];
    #pragma unroll
    for (int s = 0; s < 2; ++s) {
        #pragma unroll
        for (int mi = 0; mi < 2; ++mi) {
            int r = wr * 64 + mi * 32 + ln31;            // 0..255
            int c = lh + 2 * s;
            aoff[s * 2 + mi] = (r * 4 + (c ^ ((r >> 1) & 3))) * 8;
        }
        #pragma unroll
        for (int ni = 0; ni < 2; ++ni) {
            int rn = wc * 64 + ni * 32 + ln31;           // 0..127
            int c = lh + 2 * s;
            boff[s * 2 + ni] = 8192 + (rn * 4 + (c ^ ((rn >> 1) & 3))) * 8;
        }
    }

    f32x16 acc[2][2];
    #pragma unroll
    for (int mi = 0; mi < 2; ++mi)
        #pragma unroll
        for (int ni = 0; ni < 2; ++ni)
            acc[mi][ni] = (f32x16)(0.f);

    STAGE(0, 0); STAGE(1, 1);
    int cur = 0;                 // buffer holding tile t
    int nxt2 = 2;                // buffer to stage tile t+2 into
    #define KLOOP(W0, W1, WS, W30, W31, DOCMB) \
    for (int t = 0; t < 32; ++t) { \
        if (t < 30) STAGE(t + 2, nxt2); \
        if (t == 0)       asm volatile("s_waitcnt vmcnt(" #W0 ")" ::: "memory"); \
        else if (t == 1)  asm volatile("s_waitcnt vmcnt(" #W1 ")" ::: "memory"); \
        else if (t < 30)  asm volatile("s_waitcnt vmcnt(" #WS ")" ::: "memory"); \
        else if (t == 30) asm volatile("s_waitcnt vmcnt(" #W30 ")" ::: "memory"); \
        else              asm volatile("s_waitcnt vmcnt(" #W31 ")" ::: "memory"); \
        __builtin_amdgcn_s_barrier();           /* all waves' tile-t loads landed */ \
        __builtin_amdgcn_sched_barrier(0); \
        { \
            const short* L = &lds[cur][0]; \
            __builtin_amdgcn_s_setprio(1); \
            _Pragma("unroll") \
            for (int s = 0; s < 2; ++s) { \
                short8 af[2], bfr[2]; \
                _Pragma("unroll") \
                for (int ni = 0; ni < 2; ++ni) bfr[ni] = *(const short8*)(L + boff[s * 2 + ni]); \
                _Pragma("unroll") \
                for (int mi = 0; mi < 2; ++mi) af[mi] = *(const short8*)(L + aoff[s * 2 + mi]); \
                _Pragma("unroll") \
                for (int mi = 0; mi < 2; ++mi) \
                    _Pragma("unroll") \
                    for (int ni = 0; ni < 2; ++ni) \
                        acc[mi][ni] = __builtin_amdgcn_mfma_f32_32x32x16_bf16(af[mi], bfr[ni], acc[mi][ni], 0, 0, 0); \
            } \
            __builtin_amdgcn_s_setprio(0); \
        } \
        if (DOCMB) CSTORE();                    /* exactly 1 store/iter when enabled */ \
        __builtin_amdgcn_sched_barrier(0); \
        asm volatile("" ::: "memory"); \
        __builtin_amdgcn_s_barrier();           /* buf[cur] free for re-stage next iter */ \
        asm volatile("" ::: "memory"); \
        cur = (cur == 2) ? 0 : cur + 1; \
        nxt2 = (nxt2 == 2) ? 0 : nxt2 + 1; \
    }

    if (has_cmb) {
        KLOOP(6, 7, 8, 5, 2, 1);
    } else {
        KLOOP(6, 6, 6, 3, 0, 0);
    }
    #undef KLOOP
    #undef STAGE

    // epilogue: out tile + remaining 8 combine stores
    #pragma unroll
    for (int ni = 0; ni < 2; ++ni) {
        int c = wc * 64 + ni * 32 + ln31;
        float bv = bias[e * DFF + nt * 128 + c];
        #pragma unroll
        for (int mi = 0; mi < 2; ++mi) {
            #pragma unroll
            for (int reg = 0; reg < 16; ++reg) {
                int r = wr * 64 + mi * 32 + (reg & 3) + 8 * (reg >> 2) + 4 * lh;
                __builtin_nontemporal_store(acc[mi][ni][reg] + bv,
                    orow + (size_t)r * DFF + c);
            }
        }
    }
    if (has_cmb) { while (ntok < 8) CSTORE(); }
    #undef CSTORE
}

// ---------------- standalone combine (fallback when ws too small) ----------------
__global__ __launch_bounds__(256) void combine_kernel(const int* __restrict__ pos,
        const float* __restrict__ probs8, float* __restrict__ cmb) {
    int tok = blockIdx.x;
    int p = pos[tok];
    int e = p / CAP;
    float val = probs8[tok * 8 + (e < 0 ? 0 : e)];
    f4* row = (f4*)(cmb + (size_t)tok * ECAP);
    #pragma unroll
    for (int k = 0; k < 10; ++k) {
        int c = threadIdx.x + k * 256;
        int b4 = c * 4;
        f4 v;
        v.x = (b4 + 0 == p) ? val : 0.f;
        v.y = (b4 + 1 == p) ? val : 0.f;
        v.z = (b4 + 2 == p) ? val : 0.f;
        v.w = (b4 + 3 == p) ? val : 0.f;
        __builtin_nontemporal_store(v, row + c);
    }
}

extern "C" void kernel_launch(void* const* d_in, const int* in_sizes, int n_in,
                              void* d_out, int out_size, void* d_ws, size_t ws_size,
                              hipStream_t stream) {
    const float* x  = (const float*)d_in[0];
    const float* gw = (const float*)d_in[1];
    const float* ew = (const float*)d_in[2];
    const float* eb = (const float*)d_in[3];

    float* out = (float*)d_out;                 // [8][1280][4096]
    float* cmb = out + OUT_ELEMS;               // [8192][8][1280]
    float* laux_out = cmb + CMB_ELEMS;          // scalar

    // small scratch at the head of d_ws
    float* probs8 = (float*)d_ws;               // 8192*8
    int* top1 = (int*)(probs8 + TOKENS * 8);    // 8192
    int* slot_token = top1 + TOKENS;            // 10240
    int* pos = slot_token + ECAP;               // 8192
    int* cnts = pos + TOKENS;                   // 8

    // big bf16 scratch: prefer d_ws (enables in-gemm combine overlap);
    // fall back to the cmb region (then combine runs standalone after gemm).
    const size_t SMALL = 1 << 20;
    const size_t WT_ELEMS_ = (size_t)NE * DFF * DM;          // 33,554,432 ushort
    const size_t XBF_ELEMS_ = (size_t)(TOKENS + 1) * DM;     //  8,389,632 ushort
    bool big_ws = ws_size >= SMALL + (WT_ELEMS_ + XBF_ELEMS_) * sizeof(ushort);
    ushort* wtbf = big_ws ? (ushort*)((char*)d_ws + SMALL) : (ushort*)cmb;
    ushort* xbf  = wtbf + WT_ELEMS_;

    gate_kernel<<<TOKENS / 4, 256, 0, stream>>>(x, gw, probs8, top1, xbf);
    cvtw_rank_kernel<<<16385, 512, 0, stream>>>(ew, wtbf, top1, probs8,
                                                slot_token, pos, cnts, laux_out);
    if (big_ws) {
        gemm_kernel<<<1280, 512, 0, stream>>>(xbf, wtbf, eb, slot_token, cnts, out,
                                              pos, probs8, cmb, 1);
    } else {
        gemm_kernel<<<1280, 512, 0, stream>>>(xbf, wtbf, eb, slot_token, cnts, out,
                                              pos, probs8, cmb, 0);
        combine_kernel<<<TOKENS, 256, 0, stream>>>(pos, probs8, cmb);
    }
}